// Round 7
// baseline (1495.713 us; speedup 1.0000x reference)
//
#include <hip/hip_runtime.h>
#include <hip/hip_bf16.h>
#include <stdint.h>

#define DIM 128
#define NBLK 8
#define BS 16
#define NREL 8
#define NPB 16          // nodes per bucket (owner-computes granularity)
#define NPB_SHIFT 4
#define ENT_STAGE 256   // entries staged in LDS per chunk

typedef unsigned int u32;
typedef unsigned long long u64;

// ---------------------------------------------------------------------------
// node_keep_mask dtype detection (stable since round 1).
//   mode 0 = int32, 1 = uint8, 2 = uint16/bf16, 3 = float32
// ---------------------------------------------------------------------------
__global__ void detect_mask_kernel(const unsigned char* __restrict__ m,
                                   int* __restrict__ mode_out) {
    if (threadIdx.x != 0 || blockIdx.x != 0) return;
    bool f3f_pos1 = false, f3f = false, odd_nz = false;
    for (int i = 0; i < 512; ++i) {
        unsigned char b = m[i];
        if (b == 0x3F) { f3f = true; if ((i & 3) == 1) f3f_pos1 = true; }
        if ((i & 1) == 1 && b != 0) odd_nz = true;
    }
    int mode;
    if (f3f_pos1)      mode = 2;
    else if (f3f)      mode = 3;
    else if (odd_nz)   mode = 1;
    else               mode = 0;
    *mode_out = mode;
}

__device__ __forceinline__ bool mask_keep(const void* mask, int n, int mode) {
    switch (mode) {
        case 0:  return ((const int*)mask)[n] != 0;
        case 1:  return ((const unsigned char*)mask)[n] != 0;
        case 2:  return ((const unsigned short*)mask)[n] != 0;
        default: return ((const float*)mask)[n] != 0.0f;
    }
}

// ---------------------------------------------------------------------------
__global__ void zero_kernel(int* __restrict__ p, int n) {
    int i = blockIdx.x * blockDim.x + threadIdx.x;
    if (i < n) p[i] = 0;
}

__global__ void count_kernel(const int* __restrict__ src, const int* __restrict__ tgt,
                             const int* __restrict__ et, int* __restrict__ cnt, int nE) {
    int e = blockIdx.x * 256 + threadIdx.x;
    if (e >= nE) return;
    int s = src[e], t = tgt[e], r = et[e];
    atomicAdd(&cnt[((t >> NPB_SHIFT) << 3) + r], 1);   // fwd message owned by t
    atomicAdd(&cnt[((s >> NPB_SHIFT) << 3) + r], 1);   // bwd message owned by s
}

__global__ void scan_kernel(const int* __restrict__ cnt, int* __restrict__ off,
                            int* __restrict__ cursor, int nsb) {
    __shared__ int sums[256];
    const int t = threadIdx.x;
    const int ch = (nsb + 255) >> 8;
    const int lo = t * ch;
    const int hi = min(lo + ch, nsb);
    int s = 0;
    for (int i = lo; i < hi; ++i) s += cnt[i];
    sums[t] = s;
    __syncthreads();
    const int own = s;
    for (int o = 1; o < 256; o <<= 1) {
        int u = (t >= o) ? sums[t - o] : 0;
        __syncthreads();
        sums[t] += u;
        __syncthreads();
    }
    int run = sums[t] - own;
    for (int i = lo; i < hi; ++i) {
        off[i] = run; cursor[i] = run; run += cnt[i];
    }
    if (t == 255) off[nsb] = sums[255];
}

// entry = w(f32)<<32 | owner_local(4b)<<16 | other(16b)
__global__ void scatter_kernel(const int* __restrict__ src, const int* __restrict__ tgt,
                               const int* __restrict__ et, const float* __restrict__ ew,
                               int* __restrict__ cursor, u64* __restrict__ entries, int nE) {
    int e = blockIdx.x * 256 + threadIdx.x;
    if (e >= nE) return;
    int s = src[e], t = tgt[e], r = et[e];
    u64 wb = ((u64)__float_as_uint(ew[e])) << 32;
    int p1 = atomicAdd(&cursor[((t >> NPB_SHIFT) << 3) + r], 1);
    entries[p1] = wb | (u32)s | ((u32)(t & (NPB - 1)) << 16);
    int p2 = atomicAdd(&cursor[((s >> NPB_SHIFT) << 3) + r], 1);
    entries[p2] = wb | (u32)t | ((u32)(s & (NPB - 1)) << 16);
}

// ---------------------------------------------------------------------------
// Bucket kernel v3: aggregate-then-transform.
// For each (bucket, relation): S[node] += w_e * x[other]  (1 coalesced dword
// load + 1 FMA + 1 ds_add per thread per entry), then apply W_r once:
// acc[node] += W_r S[node]. Removes the per-entry 16-FMA matmul and the
// 4x dwordx4 broadcast gathers that the compiler serialized (round-5
// post-mortem: VGPR=40 proved only ~1 entry's loads in flight; latency-bound
// at 27 outstanding reqs/CU). 1-dword loads + 8 blocks/CU restore MLP.
// ---------------------------------------------------------------------------
#define DOT16S(S0, S1, S2, S3)                                                \
    (S0.x*bc[0]  + S0.y*bc[1]  + S0.z*bc[2]  + S0.w*bc[3] +                   \
     S1.x*bc[4]  + S1.y*bc[5]  + S1.z*bc[6]  + S1.w*bc[7] +                   \
     S2.x*bc[8]  + S2.y*bc[9]  + S2.z*bc[10] + S2.w*bc[11] +                  \
     S3.x*bc[12] + S3.y*bc[13] + S3.z*bc[14] + S3.w*bc[15])

__launch_bounds__(256, 8)
__global__ void bucket_kernel(const float* __restrict__ x,
                              const float* __restrict__ blocks,
                              const void* __restrict__ mask,
                              const int* __restrict__ mode_p,
                              const int* __restrict__ off,
                              const u64* __restrict__ entries,
                              float* __restrict__ out,
                              int n_nodes) {
    __shared__ float acc[NPB][DIM];    // 8 KB — final per-node output
    __shared__ float S[NPB][DIM];      // 8 KB — per-relation aggregate
    __shared__ u64 ent_s[ENT_STAGE];   // 2 KB
    const int tid  = threadIdx.x;
    const int g    = tid >> 7;         // 0..1: entry-lane group
    const int d    = tid & (DIM - 1);
    const int blk  = d >> 4, j = d & 15;
    const int b    = blockIdx.x;
    const int nb0  = b << NPB_SHIFT;
    const int mode = *mode_p;

    // ---- self transform: stage x rows coalesced into S, then W8 ----
    #pragma unroll
    for (int it = 0; it < NPB / 2; ++it) {
        const int ln = (it << 1) + g;
        const int n  = nb0 + ln;
        S[ln][d] = (n < n_nodes) ? x[((size_t)n << 7) + d] : 0.0f;
    }
    __syncthreads();
    {
        const float* Bp = blocks + ((NREL * NBLK + blk) << 8) + j;
        float bc[16];
        #pragma unroll
        for (int i = 0; i < 16; ++i) bc[i] = Bp[i << 4];
        #pragma unroll
        for (int p = 0; p < NPB / 2; ++p) {
            const int ln = (p << 1) + g;
            const int n  = nb0 + ln;
            const float4* Sp = (const float4*)&S[ln][blk << 4];
            const float4 s0 = Sp[0], s1 = Sp[1], s2 = Sp[2], s3 = Sp[3];
            const float v = DOT16S(s0, s1, s2, s3);
            acc[ln][d] = (n < n_nodes && mask_keep(mask, n, mode)) ? v : 0.0f;
        }
    }
    __syncthreads();   // acc ready; S free for relation aggregates

    // ---- relation-segmented aggregate + transform ----
    const int sbase = b << 3;
    for (int r = 0; r < NREL; ++r) {
        const int st = off[sbase + r];
        const int en = off[sbase + r + 1];
        if (en <= st) continue;        // wave-uniform per block

        // zero S + prefetch this relation's B column
        #pragma unroll
        for (int it = 0; it < NPB / 2; ++it) S[(it << 1) + g][d] = 0.0f;
        const float* Bp = blocks + (((r << 3) + blk) << 8) + j;
        float bc[16];
        #pragma unroll
        for (int i = 0; i < 16; ++i) bc[i] = Bp[i << 4];
        __syncthreads();

        for (int base = st; base < en; base += ENT_STAGE) {
            const int m = min(ENT_STAGE, en - base);
            if (tid < m) ent_s[tid] = entries[base + tid];
            __syncthreads();

            int k = g;
            for (; k + 6 < m; k += 8) {            // 4 entries per group-iter
                const u64 e0 = ent_s[k],     e1 = ent_s[k + 2];
                const u64 e2 = ent_s[k + 4], e3 = ent_s[k + 6];
                // 1-dword coalesced gathers — 4 independent, 1 VGPR each
                const float x0 = x[((size_t)(u32)(e0 & 0xFFFFu) << 7) + d];
                const float x1 = x[((size_t)(u32)(e1 & 0xFFFFu) << 7) + d];
                const float x2 = x[((size_t)(u32)(e2 & 0xFFFFu) << 7) + d];
                const float x3 = x[((size_t)(u32)(e3 & 0xFFFFu) << 7) + d];
                atomicAdd(&S[(int)((e0 >> 16) & (NPB - 1))][d],
                          __uint_as_float((u32)(e0 >> 32)) * x0);
                atomicAdd(&S[(int)((e1 >> 16) & (NPB - 1))][d],
                          __uint_as_float((u32)(e1 >> 32)) * x1);
                atomicAdd(&S[(int)((e2 >> 16) & (NPB - 1))][d],
                          __uint_as_float((u32)(e2 >> 32)) * x2);
                atomicAdd(&S[(int)((e3 >> 16) & (NPB - 1))][d],
                          __uint_as_float((u32)(e3 >> 32)) * x3);
            }
            for (; k < m; k += 2) {                // tail
                const u64 e0 = ent_s[k];
                const float x0 = x[((size_t)(u32)(e0 & 0xFFFFu) << 7) + d];
                atomicAdd(&S[(int)((e0 >> 16) & (NPB - 1))][d],
                          __uint_as_float((u32)(e0 >> 32)) * x0);
            }
            __syncthreads();   // ent_s reuse guard + S atomics drained
        }

        // transform: acc[n] += W_r S[n]
        #pragma unroll
        for (int p = 0; p < NPB / 2; ++p) {
            const int ln = (p << 1) + g;
            const float4* Sp = (const float4*)&S[ln][blk << 4];
            const float4 s0 = Sp[0], s1 = Sp[1], s2 = Sp[2], s3 = Sp[3];
            acc[ln][d] += DOT16S(s0, s1, s2, s3);
        }
        __syncthreads();       // transform reads done before next r zeroes S
    }

    // ---- coalesced writeout ----
    #pragma unroll
    for (int it = 0; it < NPB / 2; ++it) {
        const int ln = (it << 1) + g;
        const int n  = nb0 + ln;
        if (n < n_nodes) out[((size_t)n << 7) + d] = acc[ln][d];
    }
}

// ---------------------------------------------------------------------------
// Fallback path (round-1 kernels, 775 µs known-good).
// ---------------------------------------------------------------------------
__device__ __forceinline__ void atomAddF(float* p, float v) { unsafeAtomicAdd(p, v); }

__launch_bounds__(256)
__global__ void self_kernel(const float* __restrict__ x, const float* __restrict__ blocks,
                            const void* __restrict__ mask, const int* __restrict__ mode_p,
                            float* __restrict__ out, int n_nodes) {
    __shared__ float xs[2][DIM];
    const int mode  = *mode_p;
    const int local = threadIdx.x >> 7;
    const int d     = threadIdx.x & (DIM - 1);
    const int n     = blockIdx.x * 2 + local;
    const bool ok   = (n < n_nodes);
    if (ok) xs[local][d] = x[n * DIM + d];
    __syncthreads();
    if (!ok) return;
    const int b = d >> 4, j = d & (BS - 1);
    const float* B  = blocks + (8 * NBLK + b) * (BS * BS) + j;
    const float* xr = &xs[local][b * BS];
    float acc = 0.0f;
    #pragma unroll
    for (int i = 0; i < BS; ++i) acc += xr[i] * B[i * BS];
    out[n * DIM + d] = mask_keep(mask, n, mode) ? acc : 0.0f;
}

__launch_bounds__(256)
__global__ void edge_kernel(const float* __restrict__ x, const float* __restrict__ blocks,
                            const int* __restrict__ source, const int* __restrict__ target,
                            const int* __restrict__ etype, const float* __restrict__ ew,
                            float* __restrict__ out, int n_edges) {
    __shared__ float sx[2][2][DIM];
    const int local = threadIdx.x >> 7;
    const int d     = threadIdx.x & (DIM - 1);
    const int e     = blockIdx.x * 2 + local;
    const bool ok   = (e < n_edges);
    int s = 0, t = 0, r = 0;
    float w = 0.0f;
    if (ok) {
        s = source[e]; t = target[e]; r = etype[e]; w = ew[e];
        sx[local][0][d] = x[s * DIM + d];
        sx[local][1][d] = x[t * DIM + d];
    }
    __syncthreads();
    if (!ok) return;
    const int b = d >> 4, j = d & (BS - 1);
    const float* B   = blocks + (r * NBLK + b) * (BS * BS) + j;
    const float* xsr = &sx[local][0][b * BS];
    const float* xtr = &sx[local][1][b * BS];
    float af = 0.0f, ab = 0.0f;
    #pragma unroll
    for (int i = 0; i < BS; ++i) {
        const float bw = B[i * BS];
        af += xsr[i] * bw;
        ab += xtr[i] * bw;
    }
    atomAddF(&out[t * DIM + d], af * w);
    atomAddF(&out[s * DIM + d], ab * w);
}

// ---------------------------------------------------------------------------
extern "C" void kernel_launch(void* const* d_in, const int* in_sizes, int n_in,
                              void* d_out, int out_size, void* d_ws, size_t ws_size,
                              hipStream_t stream) {
    const float* x      = (const float*)d_in[0];
    const float* blocks = (const float*)d_in[1];
    const void*  mask   = d_in[2];
    const int*   source = (const int*)d_in[3];
    const int*   target = (const int*)d_in[4];
    const int*   etype  = (const int*)d_in[5];
    const float* ew     = (const float*)d_in[6];
    float*       out    = (float*)d_out;

    const int n_nodes = in_sizes[0] / DIM;
    const int n_edges = in_sizes[3];
    const int NB  = (n_nodes + NPB - 1) >> NPB_SHIFT;
    const int NSB = NB << 3;

    // ws layout
    char* ws = (char*)d_ws;
    const size_t o_cnt = 256;
    const size_t o_off = o_cnt + (((size_t)NSB * 4 + 63) & ~(size_t)63);
    const size_t o_cur = o_off + (((size_t)(NSB + 1) * 4 + 63) & ~(size_t)63);
    const size_t o_ent = (o_cur + (size_t)NSB * 4 + 255) & ~(size_t)255;
    const size_t need  = o_ent + (size_t)2 * n_edges * 8;

    int* mode = (int*)ws;
    hipLaunchKernelGGL(detect_mask_kernel, dim3(1), dim3(64), 0, stream,
                       (const unsigned char*)mask, mode);

    if (need <= ws_size && n_nodes <= 65535) {
        int* cnt    = (int*)(ws + o_cnt);
        int* offp   = (int*)(ws + o_off);
        int* cursor = (int*)(ws + o_cur);
        u64* ent    = (u64*)(ws + o_ent);

        hipLaunchKernelGGL(zero_kernel, dim3((NSB + 1023) / 1024), dim3(1024), 0, stream,
                           cnt, NSB);
        hipLaunchKernelGGL(count_kernel, dim3((n_edges + 255) / 256), dim3(256), 0, stream,
                           source, target, etype, cnt, n_edges);
        hipLaunchKernelGGL(scan_kernel, dim3(1), dim3(256), 0, stream,
                           cnt, offp, cursor, NSB);
        hipLaunchKernelGGL(scatter_kernel, dim3((n_edges + 255) / 256), dim3(256), 0, stream,
                           source, target, etype, ew, cursor, ent, n_edges);
        hipLaunchKernelGGL(bucket_kernel, dim3(NB), dim3(256), 0, stream,
                           x, blocks, mask, mode, offp, ent, out, n_nodes);
    } else {
        hipLaunchKernelGGL(self_kernel, dim3((n_nodes + 1) / 2), dim3(256), 0, stream,
                           x, blocks, mask, mode, out, n_nodes);
        hipLaunchKernelGGL(edge_kernel, dim3((n_edges + 1) / 2), dim3(256), 0, stream,
                           x, blocks, source, target, etype, ew, out, n_edges);
    }
}

// Round 8
// 540.233 us; speedup vs baseline: 2.7686x; 2.7686x over previous
//
#include <hip/hip_runtime.h>
#include <hip/hip_bf16.h>
#include <stdint.h>

#define DIM 128
#define NBLK 8
#define BS 16
#define NREL 8
#define NPB 16          // nodes per bucket (owner-computes granularity)
#define NPB_SHIFT 4
#define ENT_STAGE 256   // entries staged in LDS per chunk

typedef unsigned int u32;
typedef unsigned long long u64;

// ---------------------------------------------------------------------------
// node_keep_mask dtype detection — parallelized (round-7 version was a
// single-thread 512-iteration serial scan ~100 µs; this is ~2 µs).
//   mode 0 = int32, 1 = uint8, 2 = uint16/bf16, 3 = float32
// ---------------------------------------------------------------------------
__global__ void detect_mask_kernel(const unsigned char* __restrict__ m,
                                   int* __restrict__ mode_out) {
    const int lane = threadIdx.x;            // 64 threads, 1 block
    bool f3f_pos1 = false, f3f = false, odd_nz = false;
    for (int i = lane; i < 512; i += 64) {
        const unsigned char v = m[i];
        if (v == 0x3F) { f3f = true; if ((i & 3) == 1) f3f_pos1 = true; }
        if ((i & 1) == 1 && v != 0) odd_nz = true;
    }
    const u64 b1 = __ballot(f3f_pos1);
    const u64 b2 = __ballot(f3f);
    const u64 b3 = __ballot(odd_nz);
    if (lane == 0) {
        int mode;
        if (b1)      mode = 2;
        else if (b2) mode = 3;
        else if (b3) mode = 1;
        else         mode = 0;
        *mode_out = mode;
    }
}

__device__ __forceinline__ bool mask_keep(const void* mask, int n, int mode) {
    switch (mode) {
        case 0:  return ((const int*)mask)[n] != 0;
        case 1:  return ((const unsigned char*)mask)[n] != 0;
        case 2:  return ((const unsigned short*)mask)[n] != 0;
        default: return ((const float*)mask)[n] != 0.0f;
    }
}

// ---------------------------------------------------------------------------
__global__ void zero_kernel(int* __restrict__ p, int n) {
    int i = blockIdx.x * blockDim.x + threadIdx.x;
    if (i < n) p[i] = 0;
}

__global__ void count_kernel(const int* __restrict__ src, const int* __restrict__ tgt,
                             const int* __restrict__ et, int* __restrict__ cnt, int nE) {
    int e = blockIdx.x * 256 + threadIdx.x;
    if (e >= nE) return;
    int s = src[e], t = tgt[e], r = et[e];
    atomicAdd(&cnt[((t >> NPB_SHIFT) << 3) + r], 1);   // fwd message owned by t
    atomicAdd(&cnt[((s >> NPB_SHIFT) << 3) + r], 1);   // bwd message owned by s
}

__global__ void scan_kernel(const int* __restrict__ cnt, int* __restrict__ off,
                            int* __restrict__ cursor, int nsb) {
    __shared__ int sums[256];
    const int t = threadIdx.x;
    const int ch = (nsb + 255) >> 8;
    const int lo = t * ch;
    const int hi = min(lo + ch, nsb);
    int s = 0;
    for (int i = lo; i < hi; ++i) s += cnt[i];
    sums[t] = s;
    __syncthreads();
    const int own = s;
    for (int o = 1; o < 256; o <<= 1) {
        int u = (t >= o) ? sums[t - o] : 0;
        __syncthreads();
        sums[t] += u;
        __syncthreads();
    }
    int run = sums[t] - own;
    for (int i = lo; i < hi; ++i) {
        off[i] = run; cursor[i] = run; run += cnt[i];
    }
    if (t == 255) off[nsb] = sums[255];
}

// entry = w(f32)<<32 | owner_local(4b)<<16 | other(16b)
__global__ void scatter_kernel(const int* __restrict__ src, const int* __restrict__ tgt,
                               const int* __restrict__ et, const float* __restrict__ ew,
                               int* __restrict__ cursor, u64* __restrict__ entries, int nE) {
    int e = blockIdx.x * 256 + threadIdx.x;
    if (e >= nE) return;
    int s = src[e], t = tgt[e], r = et[e];
    u64 wb = ((u64)__float_as_uint(ew[e])) << 32;
    int p1 = atomicAdd(&cursor[((t >> NPB_SHIFT) << 3) + r], 1);
    entries[p1] = wb | (u32)s | ((u32)(t & (NPB - 1)) << 16);
    int p2 = atomicAdd(&cursor[((s >> NPB_SHIFT) << 3) + r], 1);
    entries[p2] = wb | (u32)t | ((u32)(s & (NPB - 1)) << 16);
}

// ---------------------------------------------------------------------------
// Bucket kernel v4: NO LDS ATOMICS.
// Round-7 post-mortem: v2 (per-entry matmul + acc atomics) and v3 (aggregate
// + S atomics) hit identical 1200 µs walls with 2x different VALU work — the
// invariant is 204.8M atomicAdd-on-__shared__ ops, which HIP lowers through a
// slow generic/flat path, not ds_add_f32. v4 removes them by construction:
//  - each 128-thread group g accumulates into its OWN plane S[g][16][128]
//    with plain += (each (entry,dim) handled by exactly one thread; the 4
//    unrolled entries are sequential in that thread → race-free);
//  - per-relation transform sums both planes: racc[p] += W_r (S[0]+S[1]);
//  - accumulator racc[8] lives in registers (rows ln = 2p+g per thread).
// LDS = 16 KB S + 2 KB entries = 18.25 KB.
// ---------------------------------------------------------------------------
#define DOT16S(S0, S1, S2, S3)                                                \
    (S0.x*bc[0]  + S0.y*bc[1]  + S0.z*bc[2]  + S0.w*bc[3] +                   \
     S1.x*bc[4]  + S1.y*bc[5]  + S1.z*bc[6]  + S1.w*bc[7] +                   \
     S2.x*bc[8]  + S2.y*bc[9]  + S2.z*bc[10] + S2.w*bc[11] +                  \
     S3.x*bc[12] + S3.y*bc[13] + S3.z*bc[14] + S3.w*bc[15])

__launch_bounds__(256, 6)
__global__ void bucket_kernel(const float* __restrict__ x,
                              const float* __restrict__ blocks,
                              const void* __restrict__ mask,
                              const int* __restrict__ mode_p,
                              const int* __restrict__ off,
                              const u64* __restrict__ entries,
                              float* __restrict__ out,
                              int n_nodes) {
    __shared__ float S[2][NPB][DIM];   // 16 KB: plane g written only by group g
    __shared__ u64 ent_s[ENT_STAGE];   // 2 KB
    const int tid  = threadIdx.x;
    const int g    = tid >> 7;         // 0..1: thread group
    const int d    = tid & (DIM - 1);
    const int blk  = d >> 4, j = d & 15;
    const int b    = blockIdx.x;
    const int nb0  = b << NPB_SHIFT;
    const int mode = *mode_p;

    float racc[NPB / 2];               // rows ln = 2p+g, in registers

    // ---- self transform straight into registers ----
    {
        const float* Bp = blocks + ((NREL * NBLK + blk) << 8) + j;
        float bc[16];
        #pragma unroll
        for (int i = 0; i < 16; ++i) bc[i] = Bp[i << 4];
        #pragma unroll
        for (int p = 0; p < NPB / 2; ++p) {
            const int n = nb0 + (p << 1) + g;
            float v = 0.0f;
            if (n < n_nodes && mask_keep(mask, n, mode)) {
                const float4* xp = (const float4*)(x + ((size_t)n << 7) + (blk << 4));
                const float4 s0 = xp[0], s1 = xp[1], s2 = xp[2], s3 = xp[3];
                v = DOT16S(s0, s1, s2, s3);
            }
            racc[p] = v;
        }
    }

    // ---- relation-segmented aggregate (plain +=) + transform ----
    const int sbase = b << 3;
    for (int r = 0; r < NREL; ++r) {
        const int st = off[sbase + r];
        const int en = off[sbase + r + 1];
        if (en <= st) continue;        // block-uniform

        // zero own plane (same threads later RMW the same addresses → in-order)
        #pragma unroll
        for (int o = 0; o < NPB; ++o) S[g][o][d] = 0.0f;

        for (int base = st; base < en; base += ENT_STAGE) {
            const int m = min(ENT_STAGE, en - base);
            if (tid < m) ent_s[tid] = entries[base + tid];
            __syncthreads();

            int k = g;
            for (; k + 6 < m; k += 8) {            // 4 entries per group-iter
                const u64 e0 = ent_s[k],     e1 = ent_s[k + 2];
                const u64 e2 = ent_s[k + 4], e3 = ent_s[k + 6];
                const float x0 = x[((size_t)(u32)(e0 & 0xFFFFu) << 7) + d];
                const float x1 = x[((size_t)(u32)(e1 & 0xFFFFu) << 7) + d];
                const float x2 = x[((size_t)(u32)(e2 & 0xFFFFu) << 7) + d];
                const float x3 = x[((size_t)(u32)(e3 & 0xFFFFu) << 7) + d];
                S[g][(int)((e0 >> 16) & (NPB - 1))][d] += __uint_as_float((u32)(e0 >> 32)) * x0;
                S[g][(int)((e1 >> 16) & (NPB - 1))][d] += __uint_as_float((u32)(e1 >> 32)) * x1;
                S[g][(int)((e2 >> 16) & (NPB - 1))][d] += __uint_as_float((u32)(e2 >> 32)) * x2;
                S[g][(int)((e3 >> 16) & (NPB - 1))][d] += __uint_as_float((u32)(e3 >> 32)) * x3;
            }
            for (; k < m; k += 2) {                // tail
                const u64 e0 = ent_s[k];
                const float x0 = x[((size_t)(u32)(e0 & 0xFFFFu) << 7) + d];
                S[g][(int)((e0 >> 16) & (NPB - 1))][d] += __uint_as_float((u32)(e0 >> 32)) * x0;
            }
            __syncthreads();   // ent_s reuse + both planes complete
        }

        // transform: racc[p] += W_r (S[0][ln] + S[1][ln]), ln = 2p+g
        {
            const float* Bp = blocks + (((r << 3) + blk) << 8) + j;
            float bc[16];
            #pragma unroll
            for (int i = 0; i < 16; ++i) bc[i] = Bp[i << 4];
            #pragma unroll
            for (int p = 0; p < NPB / 2; ++p) {
                const int ln = (p << 1) + g;
                const float4* S0 = (const float4*)&S[0][ln][blk << 4];
                const float4* S1 = (const float4*)&S[1][ln][blk << 4];
                const float4 a0 = S0[0], a1 = S0[1], a2 = S0[2], a3 = S0[3];
                const float4 b0 = S1[0], b1 = S1[1], b2 = S1[2], b3 = S1[3];
                racc[p] += DOT16S(a0, a1, a2, a3) + DOT16S(b0, b1, b2, b3);
            }
        }
        __syncthreads();       // transform reads done before next r zeroes S
    }

    // ---- coalesced writeout from registers ----
    #pragma unroll
    for (int p = 0; p < NPB / 2; ++p) {
        const int n = nb0 + (p << 1) + g;
        if (n < n_nodes) out[((size_t)n << 7) + d] = racc[p];
    }
}

// ---------------------------------------------------------------------------
// Fallback path (round-1 kernels, 775 µs known-good).
// ---------------------------------------------------------------------------
__device__ __forceinline__ void atomAddF(float* p, float v) { unsafeAtomicAdd(p, v); }

__launch_bounds__(256)
__global__ void self_kernel(const float* __restrict__ x, const float* __restrict__ blocks,
                            const void* __restrict__ mask, const int* __restrict__ mode_p,
                            float* __restrict__ out, int n_nodes) {
    __shared__ float xs[2][DIM];
    const int mode  = *mode_p;
    const int local = threadIdx.x >> 7;
    const int d     = threadIdx.x & (DIM - 1);
    const int n     = blockIdx.x * 2 + local;
    const bool ok   = (n < n_nodes);
    if (ok) xs[local][d] = x[n * DIM + d];
    __syncthreads();
    if (!ok) return;
    const int b = d >> 4, j = d & (BS - 1);
    const float* B  = blocks + (8 * NBLK + b) * (BS * BS) + j;
    const float* xr = &xs[local][b * BS];
    float acc = 0.0f;
    #pragma unroll
    for (int i = 0; i < BS; ++i) acc += xr[i] * B[i * BS];
    out[n * DIM + d] = mask_keep(mask, n, mode) ? acc : 0.0f;
}

__launch_bounds__(256)
__global__ void edge_kernel(const float* __restrict__ x, const float* __restrict__ blocks,
                            const int* __restrict__ source, const int* __restrict__ target,
                            const int* __restrict__ etype, const float* __restrict__ ew,
                            float* __restrict__ out, int n_edges) {
    __shared__ float sx[2][2][DIM];
    const int local = threadIdx.x >> 7;
    const int d     = threadIdx.x & (DIM - 1);
    const int e     = blockIdx.x * 2 + local;
    const bool ok   = (e < n_edges);
    int s = 0, t = 0, r = 0;
    float w = 0.0f;
    if (ok) {
        s = source[e]; t = target[e]; r = etype[e]; w = ew[e];
        sx[local][0][d] = x[s * DIM + d];
        sx[local][1][d] = x[t * DIM + d];
    }
    __syncthreads();
    if (!ok) return;
    const int b = d >> 4, j = d & (BS - 1);
    const float* B   = blocks + (r * NBLK + b) * (BS * BS) + j;
    const float* xsr = &sx[local][0][b * BS];
    const float* xtr = &sx[local][1][b * BS];
    float af = 0.0f, ab = 0.0f;
    #pragma unroll
    for (int i = 0; i < BS; ++i) {
        const float bw = B[i * BS];
        af += xsr[i] * bw;
        ab += xtr[i] * bw;
    }
    atomAddF(&out[t * DIM + d], af * w);
    atomAddF(&out[s * DIM + d], ab * w);
}

// ---------------------------------------------------------------------------
extern "C" void kernel_launch(void* const* d_in, const int* in_sizes, int n_in,
                              void* d_out, int out_size, void* d_ws, size_t ws_size,
                              hipStream_t stream) {
    const float* x      = (const float*)d_in[0];
    const float* blocks = (const float*)d_in[1];
    const void*  mask   = d_in[2];
    const int*   source = (const int*)d_in[3];
    const int*   target = (const int*)d_in[4];
    const int*   etype  = (const int*)d_in[5];
    const float* ew     = (const float*)d_in[6];
    float*       out    = (float*)d_out;

    const int n_nodes = in_sizes[0] / DIM;
    const int n_edges = in_sizes[3];
    const int NB  = (n_nodes + NPB - 1) >> NPB_SHIFT;
    const int NSB = NB << 3;

    // ws layout
    char* ws = (char*)d_ws;
    const size_t o_cnt = 256;
    const size_t o_off = o_cnt + (((size_t)NSB * 4 + 63) & ~(size_t)63);
    const size_t o_cur = o_off + (((size_t)(NSB + 1) * 4 + 63) & ~(size_t)63);
    const size_t o_ent = (o_cur + (size_t)NSB * 4 + 255) & ~(size_t)255;
    const size_t need  = o_ent + (size_t)2 * n_edges * 8;

    int* mode = (int*)ws;
    hipLaunchKernelGGL(detect_mask_kernel, dim3(1), dim3(64), 0, stream,
                       (const unsigned char*)mask, mode);

    if (need <= ws_size && n_nodes <= 65535) {
        int* cnt    = (int*)(ws + o_cnt);
        int* offp   = (int*)(ws + o_off);
        int* cursor = (int*)(ws + o_cur);
        u64* ent    = (u64*)(ws + o_ent);

        hipLaunchKernelGGL(zero_kernel, dim3((NSB + 1023) / 1024), dim3(1024), 0, stream,
                           cnt, NSB);
        hipLaunchKernelGGL(count_kernel, dim3((n_edges + 255) / 256), dim3(256), 0, stream,
                           source, target, etype, cnt, n_edges);
        hipLaunchKernelGGL(scan_kernel, dim3(1), dim3(256), 0, stream,
                           cnt, offp, cursor, NSB);
        hipLaunchKernelGGL(scatter_kernel, dim3((n_edges + 255) / 256), dim3(256), 0, stream,
                           source, target, etype, ew, cursor, ent, n_edges);
        hipLaunchKernelGGL(bucket_kernel, dim3(NB), dim3(256), 0, stream,
                           x, blocks, mask, mode, offp, ent, out, n_nodes);
    } else {
        hipLaunchKernelGGL(self_kernel, dim3((n_nodes + 1) / 2), dim3(256), 0, stream,
                           x, blocks, mask, mode, out, n_nodes);
        hipLaunchKernelGGL(edge_kernel, dim3((n_edges + 1) / 2), dim3(256), 0, stream,
                           x, blocks, source, target, etype, ew, out, n_edges);
    }
}

// Round 9
// 411.587 us; speedup vs baseline: 3.6340x; 1.3126x over previous
//
#include <hip/hip_runtime.h>
#include <hip/hip_bf16.h>
#include <stdint.h>

#define DIM 128
#define NBLK 8
#define BS 16
#define NREL 8
#define NPB 16          // nodes per bucket
#define NPB_SHIFT 4
#define ENT_STAGE 256
#define CAP 128         // fixed per-sub-bucket capacity (mean 64, +8 sigma)
#define OVF_CAP 65536

typedef unsigned int u32;
typedef unsigned long long u64;

// ---------------------------------------------------------------------------
// node_keep_mask dtype detection (parallel, ~2 us).
//   mode 0 = int32, 1 = uint8, 2 = uint16/bf16, 3 = float32
// ---------------------------------------------------------------------------
__global__ void detect_mask_kernel(const unsigned char* __restrict__ m,
                                   int* __restrict__ mode_out) {
    const int lane = threadIdx.x;            // 64 threads, 1 block
    bool f3f_pos1 = false, f3f = false, odd_nz = false;
    for (int i = lane; i < 512; i += 64) {
        const unsigned char v = m[i];
        if (v == 0x3F) { f3f = true; if ((i & 3) == 1) f3f_pos1 = true; }
        if ((i & 1) == 1 && v != 0) odd_nz = true;
    }
    const u64 b1 = __ballot(f3f_pos1);
    const u64 b2 = __ballot(f3f);
    const u64 b3 = __ballot(odd_nz);
    if (lane == 0) {
        int mode;
        if (b1)      mode = 2;
        else if (b2) mode = 3;
        else if (b3) mode = 1;
        else         mode = 0;
        *mode_out = mode;
    }
}

__device__ __forceinline__ bool mask_keep(const void* mask, int n, int mode) {
    switch (mode) {
        case 0:  return ((const int*)mask)[n] != 0;
        case 1:  return ((const unsigned char*)mask)[n] != 0;
        case 2:  return ((const unsigned short*)mask)[n] != 0;
        default: return ((const float*)mask)[n] != 0.0f;
    }
}

__device__ __forceinline__ void atomAddF(float* p, float v) { unsafeAtomicAdd(p, v); }

// ---------------------------------------------------------------------------
__global__ void zero_kernel(int* __restrict__ p, int n) {
    int i = blockIdx.x * blockDim.x + threadIdx.x;
    if (i < n) p[i] = 0;
}

// ---------------------------------------------------------------------------
// DIRECT binning (round-9): one pass, no count/scan. cursor[sb] ends as the
// count. entry = w(f32)<<32 | owner_local(4b)<<16 | other(16b), stored at
// entries[sb*CAP + pos]. Overflow (statistically never at CAP=mean+8sigma)
// appends (edge<<1|dir) for the repair kernel.
// ---------------------------------------------------------------------------
__global__ void scatter_direct_kernel(const int* __restrict__ src, const int* __restrict__ tgt,
                                      const int* __restrict__ et, const float* __restrict__ ew,
                                      int* __restrict__ cursor, u64* __restrict__ entries,
                                      u32* __restrict__ ovf, int* __restrict__ ovf_cnt, int nE) {
    int e = blockIdx.x * 256 + threadIdx.x;
    if (e >= nE) return;
    const int s = src[e], t = tgt[e], r = et[e];
    const u64 wb = ((u64)__float_as_uint(ew[e])) << 32;
    // fwd: owner t, other s
    {
        const int sb = ((t >> NPB_SHIFT) << 3) + r;
        const int p  = atomicAdd(&cursor[sb], 1);
        if (p < CAP) entries[(size_t)sb * CAP + p] = wb | (u32)s | ((u32)(t & (NPB - 1)) << 16);
        else { int o = atomicAdd(ovf_cnt, 1); if (o < OVF_CAP) ovf[o] = ((u32)e << 1); }
    }
    // bwd: owner s, other t
    {
        const int sb = ((s >> NPB_SHIFT) << 3) + r;
        const int p  = atomicAdd(&cursor[sb], 1);
        if (p < CAP) entries[(size_t)sb * CAP + p] = wb | (u32)t | ((u32)(s & (NPB - 1)) << 16);
        else { int o = atomicAdd(ovf_cnt, 1); if (o < OVF_CAP) ovf[o] = ((u32)e << 1) | 1u; }
    }
}

// Repair kernel: applies rare overflow messages with global atomics (runs
// after bucket_kernel's plain writes; stream-ordered).
__launch_bounds__(256)
__global__ void overflow_kernel(const float* __restrict__ x, const float* __restrict__ blocks,
                                const int* __restrict__ src, const int* __restrict__ tgt,
                                const int* __restrict__ et, const float* __restrict__ ew,
                                const u32* __restrict__ ovf, const int* __restrict__ ovf_cnt,
                                float* __restrict__ out) {
    const int nov = min(*ovf_cnt, OVF_CAP);
    const int d   = threadIdx.x & (DIM - 1);
    const int blk = d >> 4, j = d & 15;
    for (int it = blockIdx.x * 2 + (threadIdx.x >> 7); it < nov; it += gridDim.x * 2) {
        const u32 code = ovf[it];
        const int e = (int)(code >> 1), dir = (int)(code & 1u);
        const int s = src[e], t = tgt[e], r = et[e];
        const float w = ew[e];
        const int owner = dir ? s : t;
        const int other = dir ? t : s;
        const float* B  = blocks + (((r << 3) + blk) << 8) + j;
        const float* xr = x + ((size_t)other << 7) + (blk << 4);
        float acc = 0.0f;
        #pragma unroll
        for (int i = 0; i < 16; ++i) acc += xr[i] * B[i << 4];
        atomAddF(&out[((size_t)owner << 7) + d], acc * w);
    }
}

// ---------------------------------------------------------------------------
// Legacy binning passes (middle fallback if ws too small for direct layout).
// ---------------------------------------------------------------------------
__global__ void count_kernel(const int* __restrict__ src, const int* __restrict__ tgt,
                             const int* __restrict__ et, int* __restrict__ cnt, int nE) {
    int e = blockIdx.x * 256 + threadIdx.x;
    if (e >= nE) return;
    int s = src[e], t = tgt[e], r = et[e];
    atomicAdd(&cnt[((t >> NPB_SHIFT) << 3) + r], 1);
    atomicAdd(&cnt[((s >> NPB_SHIFT) << 3) + r], 1);
}

__global__ void scan_kernel(const int* __restrict__ cnt, int* __restrict__ off,
                            int* __restrict__ cursor, int nsb) {
    __shared__ int sums[256];
    const int t = threadIdx.x;
    const int ch = (nsb + 255) >> 8;
    const int lo = t * ch;
    const int hi = min(lo + ch, nsb);
    int s = 0;
    for (int i = lo; i < hi; ++i) s += cnt[i];
    sums[t] = s;
    __syncthreads();
    const int own = s;
    for (int o = 1; o < 256; o <<= 1) {
        int u = (t >= o) ? sums[t - o] : 0;
        __syncthreads();
        sums[t] += u;
        __syncthreads();
    }
    int run = sums[t] - own;
    for (int i = lo; i < hi; ++i) {
        off[i] = run; cursor[i] = run; run += cnt[i];
    }
    if (t == 255) off[nsb] = sums[255];
}

__global__ void scatter_kernel(const int* __restrict__ src, const int* __restrict__ tgt,
                               const int* __restrict__ et, const float* __restrict__ ew,
                               int* __restrict__ cursor, u64* __restrict__ entries, int nE) {
    int e = blockIdx.x * 256 + threadIdx.x;
    if (e >= nE) return;
    int s = src[e], t = tgt[e], r = et[e];
    u64 wb = ((u64)__float_as_uint(ew[e])) << 32;
    int p1 = atomicAdd(&cursor[((t >> NPB_SHIFT) << 3) + r], 1);
    entries[p1] = wb | (u32)s | ((u32)(t & (NPB - 1)) << 16);
    int p2 = atomicAdd(&cursor[((s >> NPB_SHIFT) << 3) + r], 1);
    entries[p2] = wb | (u32)t | ((u32)(s & (NPB - 1)) << 16);
}

// ---------------------------------------------------------------------------
// Bucket kernel v4b: identical structure to the proven round-8 v4 (no LDS
// atomics, group-private planes, register accumulator), plus:
//  - generic segment addressing: cap>0 -> seg=entries+sb*cap, cnt=min(cap,
//    meta[sb]);   cap==0 -> legacy off[] layout;
//  - u32 gather index math (round-8 size_t casts forced 64-bit addr VALU).
// ---------------------------------------------------------------------------
#define DOT16S(S0, S1, S2, S3)                                                \
    (S0.x*bc[0]  + S0.y*bc[1]  + S0.z*bc[2]  + S0.w*bc[3] +                   \
     S1.x*bc[4]  + S1.y*bc[5]  + S1.z*bc[6]  + S1.w*bc[7] +                   \
     S2.x*bc[8]  + S2.y*bc[9]  + S2.z*bc[10] + S2.w*bc[11] +                  \
     S3.x*bc[12] + S3.y*bc[13] + S3.z*bc[14] + S3.w*bc[15])

__launch_bounds__(256, 6)
__global__ void bucket_kernel(const float* __restrict__ x,
                              const float* __restrict__ blocks,
                              const void* __restrict__ mask,
                              const int* __restrict__ mode_p,
                              const int* __restrict__ meta,   // cursor (cap>0) or off (cap==0)
                              const int cap,
                              const u64* __restrict__ entries,
                              float* __restrict__ out,
                              int n_nodes) {
    __shared__ float S[2][NPB][DIM];   // 16 KB: plane g written only by group g
    __shared__ u64 ent_s[ENT_STAGE];   // 2 KB
    const int tid  = threadIdx.x;
    const int g    = tid >> 7;         // 0..1: thread group
    const int d    = tid & (DIM - 1);
    const int blk  = d >> 4, j = d & 15;
    const int b    = blockIdx.x;
    const int nb0  = b << NPB_SHIFT;
    const int mode = *mode_p;

    float racc[NPB / 2];               // rows ln = 2p+g, in registers

    // ---- self transform straight into registers ----
    {
        const float* Bp = blocks + ((NREL * NBLK + blk) << 8) + j;
        float bc[16];
        #pragma unroll
        for (int i = 0; i < 16; ++i) bc[i] = Bp[i << 4];
        #pragma unroll
        for (int p = 0; p < NPB / 2; ++p) {
            const int n = nb0 + (p << 1) + g;
            float v = 0.0f;
            if (n < n_nodes && mask_keep(mask, n, mode)) {
                const float4* xp = (const float4*)(x + ((size_t)n << 7) + (blk << 4));
                const float4 s0 = xp[0], s1 = xp[1], s2 = xp[2], s3 = xp[3];
                v = DOT16S(s0, s1, s2, s3);
            }
            racc[p] = v;
        }
    }

    // ---- relation-segmented aggregate (plain +=) + transform ----
    const int sbase = b << 3;
    const u32 dU = (u32)d;
    for (int r = 0; r < NREL; ++r) {
        int cnt;
        const u64* __restrict__ seg;
        if (cap > 0) {
            cnt = min(cap, meta[sbase + r]);
            seg = entries + (size_t)(sbase + r) * (size_t)cap;
        } else {
            const int st = meta[sbase + r];
            cnt = meta[sbase + r + 1] - st;
            seg = entries + st;
        }
        if (cnt <= 0) continue;        // block-uniform

        // zero own plane
        #pragma unroll
        for (int o = 0; o < NPB; ++o) S[g][o][d] = 0.0f;

        for (int base = 0; base < cnt; base += ENT_STAGE) {
            const int m = min(ENT_STAGE, cnt - base);
            if (tid < m) ent_s[tid] = seg[base + tid];
            __syncthreads();

            int k = g;
            for (; k + 6 < m; k += 8) {            // 4 entries per group-iter
                const u64 e0 = ent_s[k],     e1 = ent_s[k + 2];
                const u64 e2 = ent_s[k + 4], e3 = ent_s[k + 6];
                const float x0 = x[(((u32)e0 & 0xFFFFu) << 7) + dU];
                const float x1 = x[(((u32)e1 & 0xFFFFu) << 7) + dU];
                const float x2 = x[(((u32)e2 & 0xFFFFu) << 7) + dU];
                const float x3 = x[(((u32)e3 & 0xFFFFu) << 7) + dU];
                S[g][(int)((e0 >> 16) & (NPB - 1))][d] += __uint_as_float((u32)(e0 >> 32)) * x0;
                S[g][(int)((e1 >> 16) & (NPB - 1))][d] += __uint_as_float((u32)(e1 >> 32)) * x1;
                S[g][(int)((e2 >> 16) & (NPB - 1))][d] += __uint_as_float((u32)(e2 >> 32)) * x2;
                S[g][(int)((e3 >> 16) & (NPB - 1))][d] += __uint_as_float((u32)(e3 >> 32)) * x3;
            }
            for (; k < m; k += 2) {                // tail
                const u64 e0 = ent_s[k];
                const float x0 = x[(((u32)e0 & 0xFFFFu) << 7) + dU];
                S[g][(int)((e0 >> 16) & (NPB - 1))][d] += __uint_as_float((u32)(e0 >> 32)) * x0;
            }
            __syncthreads();   // ent_s reuse + both planes complete
        }

        // transform: racc[p] += W_r (S[0][ln] + S[1][ln]), ln = 2p+g
        {
            const float* Bp = blocks + (((r << 3) + blk) << 8) + j;
            float bc[16];
            #pragma unroll
            for (int i = 0; i < 16; ++i) bc[i] = Bp[i << 4];
            #pragma unroll
            for (int p = 0; p < NPB / 2; ++p) {
                const int ln = (p << 1) + g;
                const float4* S0 = (const float4*)&S[0][ln][blk << 4];
                const float4* S1 = (const float4*)&S[1][ln][blk << 4];
                const float4 a0 = S0[0], a1 = S0[1], a2 = S0[2], a3 = S0[3];
                const float4 b0 = S1[0], b1 = S1[1], b2 = S1[2], b3 = S1[3];
                racc[p] += DOT16S(a0, a1, a2, a3) + DOT16S(b0, b1, b2, b3);
            }
        }
        __syncthreads();       // transform reads done before next r zeroes S
    }

    // ---- coalesced writeout from registers ----
    #pragma unroll
    for (int p = 0; p < NPB / 2; ++p) {
        const int n = nb0 + (p << 1) + g;
        if (n < n_nodes) out[((size_t)n << 7) + d] = racc[p];
    }
}

// ---------------------------------------------------------------------------
// Round-1 fallback (known-good 775 us) if ws is too small for any binning.
// ---------------------------------------------------------------------------
__launch_bounds__(256)
__global__ void self_kernel(const float* __restrict__ x, const float* __restrict__ blocks,
                            const void* __restrict__ mask, const int* __restrict__ mode_p,
                            float* __restrict__ out, int n_nodes) {
    __shared__ float xs[2][DIM];
    const int mode  = *mode_p;
    const int local = threadIdx.x >> 7;
    const int d     = threadIdx.x & (DIM - 1);
    const int n     = blockIdx.x * 2 + local;
    const bool ok   = (n < n_nodes);
    if (ok) xs[local][d] = x[n * DIM + d];
    __syncthreads();
    if (!ok) return;
    const int b = d >> 4, j = d & (BS - 1);
    const float* B  = blocks + (8 * NBLK + b) * (BS * BS) + j;
    const float* xr = &xs[local][b * BS];
    float acc = 0.0f;
    #pragma unroll
    for (int i = 0; i < BS; ++i) acc += xr[i] * B[i * BS];
    out[n * DIM + d] = mask_keep(mask, n, mode) ? acc : 0.0f;
}

__launch_bounds__(256)
__global__ void edge_kernel(const float* __restrict__ x, const float* __restrict__ blocks,
                            const int* __restrict__ source, const int* __restrict__ target,
                            const int* __restrict__ etype, const float* __restrict__ ew,
                            float* __restrict__ out, int n_edges) {
    __shared__ float sx[2][2][DIM];
    const int local = threadIdx.x >> 7;
    const int d     = threadIdx.x & (DIM - 1);
    const int e     = blockIdx.x * 2 + local;
    const bool ok   = (e < n_edges);
    int s = 0, t = 0, r = 0;
    float w = 0.0f;
    if (ok) {
        s = source[e]; t = target[e]; r = etype[e]; w = ew[e];
        sx[local][0][d] = x[s * DIM + d];
        sx[local][1][d] = x[t * DIM + d];
    }
    __syncthreads();
    if (!ok) return;
    const int b = d >> 4, j = d & (BS - 1);
    const float* B   = blocks + (r * NBLK + b) * (BS * BS) + j;
    const float* xsr = &sx[local][0][b * BS];
    const float* xtr = &sx[local][1][b * BS];
    float af = 0.0f, ab = 0.0f;
    #pragma unroll
    for (int i = 0; i < BS; ++i) {
        const float bw = B[i * BS];
        af += xsr[i] * bw;
        ab += xtr[i] * bw;
    }
    atomAddF(&out[t * DIM + d], af * w);
    atomAddF(&out[s * DIM + d], ab * w);
}

// ---------------------------------------------------------------------------
extern "C" void kernel_launch(void* const* d_in, const int* in_sizes, int n_in,
                              void* d_out, int out_size, void* d_ws, size_t ws_size,
                              hipStream_t stream) {
    const float* x      = (const float*)d_in[0];
    const float* blocks = (const float*)d_in[1];
    const void*  mask   = d_in[2];
    const int*   source = (const int*)d_in[3];
    const int*   target = (const int*)d_in[4];
    const int*   etype  = (const int*)d_in[5];
    const float* ew     = (const float*)d_in[6];
    float*       out    = (float*)d_out;

    const int n_nodes = in_sizes[0] / DIM;
    const int n_edges = in_sizes[3];
    const int NB  = (n_nodes + NPB - 1) >> NPB_SHIFT;
    const int NSB = NB << 3;

    char* ws = (char*)d_ws;
    int* mode = (int*)ws;
    hipLaunchKernelGGL(detect_mask_kernel, dim3(1), dim3(64), 0, stream,
                       (const unsigned char*)mask, mode);

    // --- direct layout: cursor[NSB] + ovf_cnt | ovf[OVF_CAP] | entries[NSB*CAP]
    const size_t o_cur  = 256;
    const size_t o_ovf  = (o_cur + (size_t)(NSB + 1) * 4 + 255) & ~(size_t)255;
    const size_t o_entD = (o_ovf + (size_t)OVF_CAP * 4 + 1023) & ~(size_t)1023;
    const size_t needD  = o_entD + (size_t)NSB * CAP * 8;

    // --- legacy layout: cnt | off | cursor | entries (exact)
    const size_t l_cnt = 256;
    const size_t l_off = l_cnt + (((size_t)NSB * 4 + 63) & ~(size_t)63);
    const size_t l_cur = l_off + (((size_t)(NSB + 1) * 4 + 63) & ~(size_t)63);
    const size_t l_ent = (l_cur + (size_t)NSB * 4 + 255) & ~(size_t)255;
    const size_t needL = l_ent + (size_t)2 * n_edges * 8;

    if (needD <= ws_size && n_nodes <= 65535) {
        int* cursor  = (int*)(ws + o_cur);
        int* ovf_cnt = cursor + NSB;
        u32* ovf     = (u32*)(ws + o_ovf);
        u64* ent     = (u64*)(ws + o_entD);

        hipLaunchKernelGGL(zero_kernel, dim3((NSB + 1 + 1023) / 1024), dim3(1024), 0, stream,
                           cursor, NSB + 1);
        hipLaunchKernelGGL(scatter_direct_kernel, dim3((n_edges + 255) / 256), dim3(256), 0, stream,
                           source, target, etype, ew, cursor, ent, ovf, ovf_cnt, n_edges);
        hipLaunchKernelGGL(bucket_kernel, dim3(NB), dim3(256), 0, stream,
                           x, blocks, mask, mode, cursor, CAP, ent, out, n_nodes);
        hipLaunchKernelGGL(overflow_kernel, dim3(64), dim3(256), 0, stream,
                           x, blocks, source, target, etype, ew, ovf, ovf_cnt, out);
    } else if (needL <= ws_size && n_nodes <= 65535) {
        int* cnt    = (int*)(ws + l_cnt);
        int* offp   = (int*)(ws + l_off);
        int* cursor = (int*)(ws + l_cur);
        u64* ent    = (u64*)(ws + l_ent);

        hipLaunchKernelGGL(zero_kernel, dim3((NSB + 1023) / 1024), dim3(1024), 0, stream,
                           cnt, NSB);
        hipLaunchKernelGGL(count_kernel, dim3((n_edges + 255) / 256), dim3(256), 0, stream,
                           source, target, etype, cnt, n_edges);
        hipLaunchKernelGGL(scan_kernel, dim3(1), dim3(256), 0, stream,
                           cnt, offp, cursor, NSB);
        hipLaunchKernelGGL(scatter_kernel, dim3((n_edges + 255) / 256), dim3(256), 0, stream,
                           source, target, etype, ew, cursor, ent, n_edges);
        hipLaunchKernelGGL(bucket_kernel, dim3(NB), dim3(256), 0, stream,
                           x, blocks, mask, mode, offp, 0, ent, out, n_nodes);
    } else {
        hipLaunchKernelGGL(self_kernel, dim3((n_nodes + 1) / 2), dim3(256), 0, stream,
                           x, blocks, mask, mode, out, n_nodes);
        hipLaunchKernelGGL(edge_kernel, dim3((n_edges + 1) / 2), dim3(256), 0, stream,
                           x, blocks, source, target, etype, ew, out, n_edges);
    }
}